// Round 8
// baseline (707.252 us; speedup 1.0000x reference)
//
#include <hip/hip_runtime.h>

// HSMM forward, scaled linear recurrence.
// R8: merged single-barrier MFMA scan. Each wave owns output tiles {w, w+8};
// the MFMA D-layout (col=lane&15, rows replicated) leaves raw[z] in-register
// for the 2 z's each lane owns, so the recurrence state (win/wl) lives in the
// SAME lanes -- no raw_lds round-trip, no producer/consumer split, ONE barrier
// per step. Stale-max via 8 per-wave LDS cells (stale-by-1, same numerics as
// R7 which passed absmax=0). H prefetch distance-2 in registers across raw
// lgkm-only barriers. B-fragments of P resident (AGPR) as in R7.
// ws: H bf16[16][512][11][256]; part f32[11][64][256]; Bimg bf16 128KB;
//     Pexp f32[256][256]; logZ[11][256]; lseZ[256]; lt[11][256]; ltmz[11][256].

#define VV 50000
#define ZB 256
#define LB 11
#define BB 16
#define TB 512
#define NCHUNK 64
#define CROWS 782  // ceil(VV/NCHUNK)

typedef float v4f __attribute__((ext_vector_type(4)));
typedef short bs8 __attribute__((ext_vector_type(8)));

static __device__ __forceinline__ float bf16u_to_f(unsigned short u) {
  return __uint_as_float(((unsigned int)u) << 16);
}
static __device__ __forceinline__ unsigned short f_to_bf16u(float f) {
  unsigned int b = __float_as_uint(f);
  b += 0x7FFFu + ((b >> 16) & 1u);
  return (unsigned short)(b >> 16);
}

#define BAR() do { asm volatile("s_waitcnt lgkmcnt(0)" ::: "memory"); \
                   __builtin_amdgcn_s_barrier();                      \
                   asm volatile("" ::: "memory"); } while (0)

// ---- K1: per-chunk sum of exp(emb) over v (no-max: emb ~ N(0,1), safe in f32)
__global__ void k1_sumexp(const float* __restrict__ emb, float* __restrict__ part) {
  const int l = blockIdx.x / NCHUNK;
  const int c = blockIdx.x % NCHUNK;
  const int t = threadIdx.x;           // 512 threads
  const int zi = (t & 63) * 4;
  const int ro = t >> 6;               // 0..7
  const int v0 = c * CROWS;
  const int v1 = (v0 + CROWS < VV) ? (v0 + CROWS) : VV;
  const float* base = emb + (size_t)l * VV * ZB;
  float a0 = 0.f, a1 = 0.f, a2 = 0.f, a3 = 0.f;
  int v = v0 + ro;
  for (; v + 24 < v1; v += 32) {
    float4 x0 = *(const float4*)(base + (size_t)(v)*ZB + zi);
    float4 x1 = *(const float4*)(base + (size_t)(v + 8) * ZB + zi);
    float4 x2 = *(const float4*)(base + (size_t)(v + 16) * ZB + zi);
    float4 x3 = *(const float4*)(base + (size_t)(v + 24) * ZB + zi);
    a0 += __expf(x0.x) + __expf(x1.x) + __expf(x2.x) + __expf(x3.x);
    a1 += __expf(x0.y) + __expf(x1.y) + __expf(x2.y) + __expf(x3.y);
    a2 += __expf(x0.z) + __expf(x1.z) + __expf(x2.z) + __expf(x3.z);
    a3 += __expf(x0.w) + __expf(x1.w) + __expf(x2.w) + __expf(x3.w);
  }
  for (; v < v1; v += 8) {
    float4 x0 = *(const float4*)(base + (size_t)v * ZB + zi);
    a0 += __expf(x0.x); a1 += __expf(x0.y); a2 += __expf(x0.z); a3 += __expf(x0.w);
  }
  __shared__ float red[8][ZB];
  red[ro][zi] = a0; red[ro][zi + 1] = a1; red[ro][zi + 2] = a2; red[ro][zi + 3] = a3;
  __syncthreads();
  if (t < ZB) {
    float s = 0.f;
#pragma unroll
    for (int r = 0; r < 8; ++r) s += red[r][t];
    part[((size_t)l * NCHUNK + c) * ZB + t] = s;
  }
}

// ---- K2: combine partials -> logZ; lse over l of l_per_z; Pexp rows + Bimg
__global__ void k2_combine(const float* __restrict__ part, const float* __restrict__ zpz,
                           const float* __restrict__ lpz, float* __restrict__ logZ,
                           float* __restrict__ lseZ, float* __restrict__ Pexp,
                           unsigned short* __restrict__ Bimg) {
  const int bid = blockIdx.x;
  const int t = threadIdx.x;  // 256
  if (bid < LB) {
    float s = 0.f;
    for (int c = 0; c < NCHUNK; ++c) s += part[((size_t)bid * NCHUNK + c) * ZB + t];
    logZ[bid * ZB + t] = __logf(s);
  } else if (bid == LB) {
    float lv[LB]; float m = -1e30f;
#pragma unroll
    for (int l = 0; l < LB; ++l) { lv[l] = lpz[t * LB + l]; m = fmaxf(m, lv[l]); }
    float s = 0.f;
#pragma unroll
    for (int l = 0; l < LB; ++l) s += __expf(lv[l] - m);
    lseZ[t] = m + __logf(s);
  } else {
    const int r = bid - (LB + 1);  // z (row of P)
    const float x = zpz[r * ZB + t];
    __shared__ float sA[4], sB[4];
    float m = x;
#pragma unroll
    for (int off = 32; off >= 1; off >>= 1) m = fmaxf(m, __shfl_xor(m, off, 64));
    if ((t & 63) == 0) sA[t >> 6] = m;
    __syncthreads();
    m = fmaxf(fmaxf(sA[0], sA[1]), fmaxf(sA[2], sA[3]));
    const float e = __expf(x - m);
    float s = e;
#pragma unroll
    for (int off = 32; off >= 1; off >>= 1) s += __shfl_xor(s, off, 64);
    if ((t & 63) == 0) sB[t >> 6] = s;
    __syncthreads();
    const float tot = sB[0] + sB[1] + sB[2] + sB[3];
    const float P = e / tot;
    Pexp[r * ZB + t] = P;
    // B-fragment image for k5: frag(tile, slice), lane = g*16 + col, elem = ii
    // holds B[k = slice*32 + g*8 + ii][col] = P[r][t].
    const int tile = t >> 4, cl = t & 15;
    const int slice = r >> 5, g = (r >> 3) & 3, ii = r & 7;
    Bimg[((size_t)(tile * 8 + slice) * 64 + (g * 16 + cl)) * 8 + ii] = f_to_bf16u(P);
  }
}

// ---- K3: small tables lt = exp(l_term), ltmz = l_term - logZ
__global__ void k3_tables(const float* __restrict__ logZ, const float* __restrict__ lseZ,
                          const float* __restrict__ lpz, float* __restrict__ lt,
                          float* __restrict__ ltmz) {
  const int l = blockIdx.x; const int z = threadIdx.x;
  const float ll = lpz[z * LB + l] - lseZ[z];
  lt[l * ZB + z] = __expf(ll);
  ltmz[l * ZB + z] = ll - logZ[l * ZB + z];
}

// ---- K4: build shift-aligned exp-domain emissions H[b][n][l][z] (bf16)
__global__ void k4_build(const int* __restrict__ ng, const float* __restrict__ emb,
                         const float* __restrict__ lt, const float* __restrict__ ltmz,
                         unsigned short* __restrict__ H) {
  const int n = blockIdx.x + 1;
  const int b = blockIdx.y;
  const int z = threadIdx.x;  // 256
  unsigned short* hrow = H + ((size_t)b * TB + n) * LB * ZB + z;
#pragma unroll
  for (int l = 0; l < LB; ++l) {
    const int s = n - 1 - l;
    float h = 0.f;
    if (s >= 0) {
      const int id = ng[((size_t)l * BB + b) * TB + s];
      if (id == 0) h = lt[l * ZB + z];
      else if (id != 1) h = __expf(emb[((size_t)l * VV + id) * ZB + z] + ltmz[l * ZB + z]);
    }
    hrow[(size_t)l * ZB] = f_to_bf16u(h);
  }
}

// ---- K5: merged single-barrier scan. 512 thr/block, one block per batch b.
// wave w owns tiles {w, w+8}; lane owns z0 = w*16+(lane&15), z1 = z0+128.
__global__ __launch_bounds__(512, 1)
void k5_forward(const float* __restrict__ Pexp, const unsigned short* __restrict__ Bimg,
                const unsigned short* __restrict__ H,
                const int* __restrict__ xlen, float* __restrict__ out) {
  const int b = blockIdx.x;
  const int t = threadIdx.x;
  const int w = t >> 6;
  const int lane = t & 63;
  const int col = lane & 15;
  const int g4 = (lane >> 4) << 4;          // g*16 bytes for A-read
  const int z0 = w * 16 + col;              // tile w
  const int z1 = (w + 8) * 16 + col;        // tile w+8

  __shared__ __align__(16) unsigned short S_lds[2][ZB];  // S as bf16, dbuf
  __shared__ __align__(16) float cells[2][8];            // per-wave stale max
  __shared__ float red4[8];

  // resident B = P fragments (2 tiles x 8 slices = 64 regs; AGPR-placed)
  bs8 frag0[8], frag1[8];
#pragma unroll
  for (int s = 0; s < 8; ++s) {
    frag0[s] = *((const bs8*)Bimg + (size_t)(w * 8 + s) * 64 + lane);
    frag1[s] = *((const bs8*)Bimg + (size_t)((w + 8) * 8 + s) * 64 + lane);
    asm volatile("" : "+v"(frag0[s]), "+v"(frag1[s]));
  }

  const int xl = xlen[b];

  // m0 = max_z P[0][z]
  const float p00 = Pexp[z0], p01 = Pexp[z1];
  {
    float pm = fmaxf(p00, p01);
    pm = fmaxf(pm, __shfl_xor(pm, 1)); pm = fmaxf(pm, __shfl_xor(pm, 2));
    pm = fmaxf(pm, __shfl_xor(pm, 4)); pm = fmaxf(pm, __shfl_xor(pm, 8));
    if (lane == 0) cells[0][w] = pm;
  }
  __syncthreads();
  float m0;
  {
    const float4 cA = *(const float4*)&cells[0][0];
    const float4 cB = *(const float4*)&cells[0][4];
    m0 = fmaxf(fmaxf(fmaxf(cA.x, cA.y), fmaxf(cA.z, cA.w)),
               fmaxf(fmaxf(cB.x, cB.y), fmaxf(cB.z, cB.w)));
  }
  __syncthreads();
  if (lane == 0) { cells[0][w] = 1.f; cells[1][w] = 1.f; }

  // state init
  float win0[LB], win1[LB], wl[LB];
  float C = __logf(m0), cap0 = 0.f, cap1 = 0.f, capC = 0.f;
  win0[0] = p00 / m0; win1[0] = p01 / m0;
  wl[0] = 1.f;
#pragma unroll
  for (int l = 1; l < LB; ++l) { win0[l] = 0.f; win1[l] = 0.f; wl[l] = 0.f; }

  const unsigned short* hb0 = H + (size_t)b * TB * LB * ZB + z0;
  const unsigned short* hb1 = H + (size_t)b * TB * LB * ZB + z1;

  // S(1) = wl[0]*H(1)[l=0]*win[0]
  {
    const float S0 = bf16u_to_f(hb0[(size_t)(1 * LB) * ZB]) * win0[0];
    const float S1 = bf16u_to_f(hb1[(size_t)(1 * LB) * ZB]) * win1[0];
    if (xl == 1) { cap0 = S0; cap1 = S1; capC = C; }
    if (lane < 16) { S_lds[1][z0] = f_to_bf16u(S0); S_lds[1][z1] = f_to_bf16u(S1); }
  }

  // H prefetch: hE = H(2) (odd regions), hO = H(3) (even regions)
  unsigned short hE0[LB], hE1[LB], hO0[LB], hO1[LB];
#pragma unroll
  for (int l = 0; l < LB; ++l) {
    hE0[l] = hb0[((size_t)2 * LB + l) * ZB]; hE1[l] = hb1[((size_t)2 * LB + l) * ZB];
    hO0[l] = hb0[((size_t)3 * LB + l) * ZB]; hO1[l] = hb1[((size_t)3 * LB + l) * ZB];
  }
  BAR();  // S(1), cells init visible

  // Region r: MFMA of S(r) -> raw(r); win update; S(r+1) compute+publish.
#define REGION(rr, RB, WB, CR, CW, hx0, hx1)                                   \
  do {                                                                         \
    const bs8* ap = (const bs8*)((const char*)&S_lds[RB][0] + g4);             \
    bs8 ar[8];                                                                 \
    _Pragma("unroll")                                                          \
    for (int s = 0; s < 8; ++s) ar[s] = ap[s * 4];                             \
    v4f acc0 = {0.f, 0.f, 0.f, 0.f}, acc1 = {0.f, 0.f, 0.f, 0.f};              \
    _Pragma("unroll")                                                          \
    for (int s = 0; s < 8; ++s) {                                              \
      acc0 = __builtin_amdgcn_mfma_f32_16x16x32_bf16(ar[s], frag0[s], acc0, 0, 0, 0); \
      acc1 = __builtin_amdgcn_mfma_f32_16x16x32_bf16(ar[s], frag1[s], acc1, 0, 0, 0); \
    }                                                                          \
    const float raw0 = acc0[0], raw1 = acc1[0];                                \
    const float4 cA = *(const float4*)&cells[CR][0];                           \
    const float4 cB = *(const float4*)&cells[CR][4];                           \
    float mx = fmaxf(fmaxf(fmaxf(cA.x, cA.y), fmaxf(cA.z, cA.w)),              \
                     fmaxf(fmaxf(cB.x, cB.y), fmaxf(cB.z, cB.w)));             \
    mx = fmaxf(mx, 1e-35f);                                                    \
    const float inv = 1.0f / mx;                                               \
    const float delta = __logf(mx);                                            \
    float mw = wl[0];                                                          \
    _Pragma("unroll")                                                          \
    for (int l = 1; l < LB - 1; ++l) mw = fmaxf(mw, wl[l]);                    \
    const float a = fmaxf(delta, __logf(fmaxf(mw, 1e-37f)));                   \
    const float es = __expf(-a);                                               \
    _Pragma("unroll")                                                          \
    for (int l = LB - 1; l >= 1; --l) wl[l] = wl[l - 1] * es;                  \
    wl[0] = __expf(delta - a);                                                 \
    C += a;                                                                    \
    _Pragma("unroll")                                                          \
    for (int l = LB - 1; l >= 1; --l) { win0[l] = win0[l - 1]; win1[l] = win1[l - 1]; } \
    win0[0] = raw0 * inv; win1[0] = raw1 * inv;                                \
    {                                                                          \
      float wm = fmaxf(raw0, raw1);                                            \
      wm = fmaxf(wm, __shfl_xor(wm, 1)); wm = fmaxf(wm, __shfl_xor(wm, 2));    \
      wm = fmaxf(wm, __shfl_xor(wm, 4)); wm = fmaxf(wm, __shfl_xor(wm, 8));    \
      if (lane == 0) cells[CW][w] = wm;                                        \
    }                                                                          \
    {                                                                          \
      float S0 = 0.f, S1 = 0.f;                                                \
      _Pragma("unroll")                                                        \
      for (int l = 0; l < LB; ++l) {                                           \
        S0 = fmaf(wl[l] * bf16u_to_f(hx0[l]), win0[l], S0);                    \
        S1 = fmaf(wl[l] * bf16u_to_f(hx1[l]), win1[l], S1);                    \
      }                                                                        \
      if ((rr) + 1 == xl) { cap0 = S0; cap1 = S1; capC = C; }                  \
      if (lane < 16) {                                                         \
        S_lds[WB][z0] = f_to_bf16u(S0); S_lds[WB][z1] = f_to_bf16u(S1);        \
      }                                                                        \
    }                                                                          \
    {                                                                          \
      const int np = ((rr) + 3 <= 511) ? (rr) + 3 : 511;                       \
      _Pragma("unroll")                                                        \
      for (int l = 0; l < LB; ++l) {                                           \
        hx0[l] = hb0[((size_t)np * LB + l) * ZB];                              \
        hx1[l] = hb1[((size_t)np * LB + l) * ZB];                              \
      }                                                                        \
    }                                                                          \
    BAR();                                                                     \
  } while (0)

#pragma unroll 1
  for (int r = 1; r <= 509; r += 2) {
    REGION(r, 1, 0, 0, 1, hE0, hE1);
    REGION(r + 1, 0, 1, 1, 0, hO0, hO1);
  }
#undef REGION

  // epilogue: out[b] = capC + log(sum_z cap_z); xl==0 -> 0
  {
    float v = cap0 + cap1;
    v += __shfl_xor(v, 1); v += __shfl_xor(v, 2);
    v += __shfl_xor(v, 4); v += __shfl_xor(v, 8);
    if (lane == 0) red4[w] = v;
  }
  __syncthreads();
  if (t == 0) {
    float tot = 0.f;
#pragma unroll
    for (int i = 0; i < 8; ++i) tot += red4[i];
    out[b] = (xl == 0) ? 0.f : (__logf(tot) + capC);
  }
}

extern "C" void kernel_launch(void* const* d_in, const int* in_sizes, int n_in,
                              void* d_out, int out_size, void* d_ws, size_t ws_size,
                              hipStream_t stream) {
  (void)in_sizes; (void)n_in; (void)out_size; (void)ws_size;
  const int* xlen = (const int*)d_in[1];
  const int* ng = (const int*)d_in[2];
  const float* emb = (const float*)d_in[3];
  const float* zpz = (const float*)d_in[4];
  const float* lpz = (const float*)d_in[5];
  float* out = (float*)d_out;

  char* ws = (char*)d_ws;
  unsigned short* H = (unsigned short*)ws;
  size_t off = (size_t)BB * TB * LB * ZB * 2;
  float* part = (float*)(ws + off); off += (size_t)LB * NCHUNK * ZB * 4;
  unsigned short* Bimg = (unsigned short*)(ws + off); off += (size_t)16 * 8 * 64 * 8 * 2;
  float* Pexp = (float*)(ws + off); off += (size_t)ZB * ZB * 4;
  float* logZ = (float*)(ws + off); off += (size_t)LB * ZB * 4;
  float* lseZ = (float*)(ws + off); off += (size_t)ZB * 4;
  float* lt = (float*)(ws + off); off += (size_t)LB * ZB * 4;
  float* ltmz = (float*)(ws + off); off += (size_t)LB * ZB * 4;

  k1_sumexp<<<dim3(LB * NCHUNK), dim3(512), 0, stream>>>(emb, part);
  k2_combine<<<dim3(LB + 1 + ZB), dim3(ZB), 0, stream>>>(part, zpz, lpz, logZ, lseZ,
                                                         Pexp, Bimg);
  k3_tables<<<dim3(LB), dim3(ZB), 0, stream>>>(logZ, lseZ, lpz, lt, ltmz);
  k4_build<<<dim3(TB - 1, BB), dim3(ZB), 0, stream>>>(ng, emb, lt, ltmz, H);
  k5_forward<<<dim3(BB), dim3(512), 0, stream>>>(Pexp, Bimg, H, xlen, out);
}

// Round 9
// 599.128 us; speedup vs baseline: 1.1805x; 1.1805x over previous
//
#include <hip/hip_runtime.h>

// HSMM forward, scaled linear recurrence.
// R9: merged single-barrier MFMA scan (R8 structure, absmax 0) with the
// register budget fixed: (1) P fragments pinned to AGPRs ("a" constraint;
// MFMA reads B from AGPR on gfx950) freeing 64 arch VGPRs; (2) H packed as
// bf16-PAIRS (layout [b][n][z][12], u32 pairs): 3 uint2 loads + 6 regs per
// buffer instead of 11 scalar loads + 11 regs. R8's spill of the state
// arrays (VGPR_Count=104 < frag's 64 + state ~130) was the 2650 cyc/step.
// ws: H2 u32[16][512][256][6] (48MiB); part f32[11][64][256]; Bimg bf16 128KB;
//     Pexp f32[256][256]; logZ[11][256]; lseZ[256]; lt[11][256]; ltmz[11][256].

#define VV 50000
#define ZB 256
#define LB 11
#define BB 16
#define TB 512
#define NCHUNK 64
#define CROWS 782  // ceil(VV/NCHUNK)

typedef float v4f __attribute__((ext_vector_type(4)));
typedef short bs8 __attribute__((ext_vector_type(8)));

static __device__ __forceinline__ float bf16u_to_f(unsigned short u) {
  return __uint_as_float(((unsigned int)u) << 16);
}
static __device__ __forceinline__ unsigned short f_to_bf16u(float f) {
  unsigned int b = __float_as_uint(f);
  b += 0x7FFFu + ((b >> 16) & 1u);
  return (unsigned short)(b >> 16);
}
static __device__ __forceinline__ void unp(unsigned int u, float& lo, float& hi) {
  lo = __uint_as_float(u << 16);
  hi = __uint_as_float(u & 0xFFFF0000u);
}

#define BAR() do { asm volatile("s_waitcnt lgkmcnt(0)" ::: "memory"); \
                   __builtin_amdgcn_s_barrier();                      \
                   asm volatile("" ::: "memory"); } while (0)

// ---- K1: per-chunk sum of exp(emb) over v (no-max: emb ~ N(0,1), safe in f32)
__global__ void k1_sumexp(const float* __restrict__ emb, float* __restrict__ part) {
  const int l = blockIdx.x / NCHUNK;
  const int c = blockIdx.x % NCHUNK;
  const int t = threadIdx.x;           // 512 threads
  const int zi = (t & 63) * 4;
  const int ro = t >> 6;               // 0..7
  const int v0 = c * CROWS;
  const int v1 = (v0 + CROWS < VV) ? (v0 + CROWS) : VV;
  const float* base = emb + (size_t)l * VV * ZB;
  float a0 = 0.f, a1 = 0.f, a2 = 0.f, a3 = 0.f;
  int v = v0 + ro;
  for (; v + 24 < v1; v += 32) {
    float4 x0 = *(const float4*)(base + (size_t)(v)*ZB + zi);
    float4 x1 = *(const float4*)(base + (size_t)(v + 8) * ZB + zi);
    float4 x2 = *(const float4*)(base + (size_t)(v + 16) * ZB + zi);
    float4 x3 = *(const float4*)(base + (size_t)(v + 24) * ZB + zi);
    a0 += __expf(x0.x) + __expf(x1.x) + __expf(x2.x) + __expf(x3.x);
    a1 += __expf(x0.y) + __expf(x1.y) + __expf(x2.y) + __expf(x3.y);
    a2 += __expf(x0.z) + __expf(x1.z) + __expf(x2.z) + __expf(x3.z);
    a3 += __expf(x0.w) + __expf(x1.w) + __expf(x2.w) + __expf(x3.w);
  }
  for (; v < v1; v += 8) {
    float4 x0 = *(const float4*)(base + (size_t)v * ZB + zi);
    a0 += __expf(x0.x); a1 += __expf(x0.y); a2 += __expf(x0.z); a3 += __expf(x0.w);
  }
  __shared__ float red[8][ZB];
  red[ro][zi] = a0; red[ro][zi + 1] = a1; red[ro][zi + 2] = a2; red[ro][zi + 3] = a3;
  __syncthreads();
  if (t < ZB) {
    float s = 0.f;
#pragma unroll
    for (int r = 0; r < 8; ++r) s += red[r][t];
    part[((size_t)l * NCHUNK + c) * ZB + t] = s;
  }
}

// ---- K2: combine partials -> logZ; lse over l of l_per_z; Pexp rows + Bimg
__global__ void k2_combine(const float* __restrict__ part, const float* __restrict__ zpz,
                           const float* __restrict__ lpz, float* __restrict__ logZ,
                           float* __restrict__ lseZ, float* __restrict__ Pexp,
                           unsigned short* __restrict__ Bimg) {
  const int bid = blockIdx.x;
  const int t = threadIdx.x;  // 256
  if (bid < LB) {
    float s = 0.f;
    for (int c = 0; c < NCHUNK; ++c) s += part[((size_t)bid * NCHUNK + c) * ZB + t];
    logZ[bid * ZB + t] = __logf(s);
  } else if (bid == LB) {
    float lv[LB]; float m = -1e30f;
#pragma unroll
    for (int l = 0; l < LB; ++l) { lv[l] = lpz[t * LB + l]; m = fmaxf(m, lv[l]); }
    float s = 0.f;
#pragma unroll
    for (int l = 0; l < LB; ++l) s += __expf(lv[l] - m);
    lseZ[t] = m + __logf(s);
  } else {
    const int r = bid - (LB + 1);  // z (row of P)
    const float x = zpz[r * ZB + t];
    __shared__ float sA[4], sB[4];
    float m = x;
#pragma unroll
    for (int off = 32; off >= 1; off >>= 1) m = fmaxf(m, __shfl_xor(m, off, 64));
    if ((t & 63) == 0) sA[t >> 6] = m;
    __syncthreads();
    m = fmaxf(fmaxf(sA[0], sA[1]), fmaxf(sA[2], sA[3]));
    const float e = __expf(x - m);
    float s = e;
#pragma unroll
    for (int off = 32; off >= 1; off >>= 1) s += __shfl_xor(s, off, 64);
    if ((t & 63) == 0) sB[t >> 6] = s;
    __syncthreads();
    const float tot = sB[0] + sB[1] + sB[2] + sB[3];
    const float P = e / tot;
    Pexp[r * ZB + t] = P;
    // B-fragment image for k5: frag(tile, slice), lane = g*16 + col, elem = ii
    // holds B[k = slice*32 + g*8 + ii][col] = P[r][t].
    const int tile = t >> 4, cl = t & 15;
    const int slice = r >> 5, g = (r >> 3) & 3, ii = r & 7;
    Bimg[((size_t)(tile * 8 + slice) * 64 + (g * 16 + cl)) * 8 + ii] = f_to_bf16u(P);
  }
}

// ---- K3: small tables lt = exp(l_term), ltmz = l_term - logZ
__global__ void k3_tables(const float* __restrict__ logZ, const float* __restrict__ lseZ,
                          const float* __restrict__ lpz, float* __restrict__ lt,
                          float* __restrict__ ltmz) {
  const int l = blockIdx.x; const int z = threadIdx.x;
  const float ll = lpz[z * LB + l] - lseZ[z];
  lt[l * ZB + z] = __expf(ll);
  ltmz[l * ZB + z] = ll - logZ[l * ZB + z];
}

// ---- K4: build shift-aligned emissions, PAIR-PACKED: H2[b][n][z][6] (u32)
__global__ void k4_build(const int* __restrict__ ng, const float* __restrict__ emb,
                         const float* __restrict__ lt, const float* __restrict__ ltmz,
                         unsigned int* __restrict__ H2) {
  const int n = blockIdx.x + 1;
  const int b = blockIdx.y;
  const int z = threadIdx.x;  // 256
  float h[12];
#pragma unroll
  for (int l = 0; l < LB; ++l) {
    const int s = n - 1 - l;
    float hv = 0.f;
    if (s >= 0) {
      const int id = ng[((size_t)l * BB + b) * TB + s];
      if (id == 0) hv = lt[l * ZB + z];
      else if (id != 1) hv = __expf(emb[((size_t)l * VV + id) * ZB + z] + ltmz[l * ZB + z]);
    }
    h[l] = hv;
  }
  h[11] = 0.f;
  unsigned int* dst = H2 + ((size_t)(b * TB + n) * ZB + z) * 6;
#pragma unroll
  for (int i = 0; i < 6; ++i)
    dst[i] = (unsigned int)f_to_bf16u(h[2 * i]) |
             ((unsigned int)f_to_bf16u(h[2 * i + 1]) << 16);
}

// ---- K5: merged single-barrier scan. 512 thr/block, one block per batch b.
// wave w owns tiles {w, w+8}; lane owns z0 = w*16+(lane&15), z1 = z0+128.
__global__ __launch_bounds__(512, 1)
void k5_forward(const float* __restrict__ Pexp, const unsigned short* __restrict__ Bimg,
                const unsigned int* __restrict__ H2,
                const int* __restrict__ xlen, float* __restrict__ out) {
  const int b = blockIdx.x;
  const int t = threadIdx.x;
  const int w = t >> 6;
  const int lane = t & 63;
  const int col = lane & 15;
  const int g4 = (lane >> 4) << 4;          // g*16 bytes for A-read
  const int z0 = w * 16 + col;              // tile w
  const int z1 = (w + 8) * 16 + col;        // tile w+8

  __shared__ __align__(16) unsigned short S_lds[2][ZB];  // S as bf16, dbuf
  __shared__ __align__(16) float cells[2][8];            // per-wave stale max
  __shared__ float red4[8];

  // resident B = P fragments pinned to AGPRs (2 tiles x 8 slices).
  bs8 frag0[8], frag1[8];
#pragma unroll
  for (int s = 0; s < 8; ++s) {
    frag0[s] = *((const bs8*)Bimg + (size_t)(w * 8 + s) * 64 + lane);
    frag1[s] = *((const bs8*)Bimg + (size_t)((w + 8) * 8 + s) * 64 + lane);
    asm volatile("" : "+a"(frag0[s]));
    asm volatile("" : "+a"(frag1[s]));
  }

  const int xl = xlen[b];

  // m0 = max_z P[0][z]
  const float p00 = Pexp[z0], p01 = Pexp[z1];
  {
    float pm = fmaxf(p00, p01);
    pm = fmaxf(pm, __shfl_xor(pm, 1)); pm = fmaxf(pm, __shfl_xor(pm, 2));
    pm = fmaxf(pm, __shfl_xor(pm, 4)); pm = fmaxf(pm, __shfl_xor(pm, 8));
    if (lane == 0) cells[0][w] = pm;
  }
  __syncthreads();
  float m0;
  {
    const float4 cA = *(const float4*)&cells[0][0];
    const float4 cB = *(const float4*)&cells[0][4];
    m0 = fmaxf(fmaxf(fmaxf(cA.x, cA.y), fmaxf(cA.z, cA.w)),
               fmaxf(fmaxf(cB.x, cB.y), fmaxf(cB.z, cB.w)));
  }
  __syncthreads();
  if (lane == 0) { cells[0][w] = 1.f; cells[1][w] = 1.f; }

  // state init
  float win0[LB], win1[LB], wl[LB];
  float C = __logf(m0), cap0 = 0.f, cap1 = 0.f, capC = 0.f;
  win0[0] = p00 / m0; win1[0] = p01 / m0;
  wl[0] = 1.f;
#pragma unroll
  for (int l = 1; l < LB; ++l) { win0[l] = 0.f; win1[l] = 0.f; wl[l] = 0.f; }

  const unsigned int* hbase = H2 + (size_t)b * TB * ZB * 6;

  // S(1) = H(1)[l=0]*win[0]
  {
    const float S0 = bf16u_to_f((unsigned short)hbase[((size_t)1 * ZB + z0) * 6]) * win0[0];
    const float S1 = bf16u_to_f((unsigned short)hbase[((size_t)1 * ZB + z1) * 6]) * win1[0];
    if (xl == 1) { cap0 = S0; cap1 = S1; capC = C; }
    if (lane < 16) { S_lds[1][z0] = f_to_bf16u(S0); S_lds[1][z1] = f_to_bf16u(S1); }
  }

  // H prefetch buffers (uint2 x3 each): hE = H(2) (odd regions), hO = H(3)
  uint2 hE0[3], hE1[3], hO0[3], hO1[3];
#pragma unroll
  for (int i = 0; i < 3; ++i) {
    hE0[i] = ((const uint2*)(hbase + ((size_t)2 * ZB + z0) * 6))[i];
    hE1[i] = ((const uint2*)(hbase + ((size_t)2 * ZB + z1) * 6))[i];
    hO0[i] = ((const uint2*)(hbase + ((size_t)3 * ZB + z0) * 6))[i];
    hO1[i] = ((const uint2*)(hbase + ((size_t)3 * ZB + z1) * 6))[i];
  }
  BAR();  // S(1), cells init visible

  // Region r: MFMA of S(r) -> raw(r); win update; S(r+1) compute+publish.
#define SDOT(hx, win, Sv)                                                      \
  {                                                                            \
    float lo, hi;                                                              \
    unp(hx[0].x, lo, hi);                                                      \
    Sv = fmaf(wl[0] * lo, win[0], Sv); Sv = fmaf(wl[1] * hi, win[1], Sv);      \
    unp(hx[0].y, lo, hi);                                                      \
    Sv = fmaf(wl[2] * lo, win[2], Sv); Sv = fmaf(wl[3] * hi, win[3], Sv);      \
    unp(hx[1].x, lo, hi);                                                      \
    Sv = fmaf(wl[4] * lo, win[4], Sv); Sv = fmaf(wl[5] * hi, win[5], Sv);      \
    unp(hx[1].y, lo, hi);                                                      \
    Sv = fmaf(wl[6] * lo, win[6], Sv); Sv = fmaf(wl[7] * hi, win[7], Sv);      \
    unp(hx[2].x, lo, hi);                                                      \
    Sv = fmaf(wl[8] * lo, win[8], Sv); Sv = fmaf(wl[9] * hi, win[9], Sv);      \
    unp(hx[2].y, lo, hi);                                                      \
    Sv = fmaf(wl[10] * lo, win[10], Sv);                                       \
  }

#define REGION(rr, RB, WB, CR, CW, hx0, hx1)                                   \
  do {                                                                         \
    const bs8* ap = (const bs8*)((const char*)&S_lds[RB][0] + g4);             \
    bs8 ar[8];                                                                 \
    _Pragma("unroll")                                                          \
    for (int s = 0; s < 8; ++s) ar[s] = ap[s * 4];                             \
    v4f acc0 = {0.f, 0.f, 0.f, 0.f}, acc1 = {0.f, 0.f, 0.f, 0.f};              \
    _Pragma("unroll")                                                          \
    for (int s = 0; s < 8; ++s) {                                              \
      acc0 = __builtin_amdgcn_mfma_f32_16x16x32_bf16(ar[s], frag0[s], acc0, 0, 0, 0); \
      acc1 = __builtin_amdgcn_mfma_f32_16x16x32_bf16(ar[s], frag1[s], acc1, 0, 0, 0); \
    }                                                                          \
    const float raw0 = acc0[0], raw1 = acc1[0];                                \
    const float4 cA = *(const float4*)&cells[CR][0];                           \
    const float4 cB = *(const float4*)&cells[CR][4];                           \
    float mx = fmaxf(fmaxf(fmaxf(cA.x, cA.y), fmaxf(cA.z, cA.w)),              \
                     fmaxf(fmaxf(cB.x, cB.y), fmaxf(cB.z, cB.w)));             \
    mx = fmaxf(mx, 1e-35f);                                                    \
    const float inv = 1.0f / mx;                                               \
    const float delta = __logf(mx);                                            \
    float mw = wl[0];                                                          \
    _Pragma("unroll")                                                          \
    for (int l = 1; l < LB - 1; ++l) mw = fmaxf(mw, wl[l]);                    \
    const float a = fmaxf(delta, __logf(fmaxf(mw, 1e-37f)));                   \
    const float es = __expf(-a);                                               \
    _Pragma("unroll")                                                          \
    for (int l = LB - 1; l >= 1; --l) wl[l] = wl[l - 1] * es;                  \
    wl[0] = __expf(delta - a);                                                 \
    C += a;                                                                    \
    _Pragma("unroll")                                                          \
    for (int l = LB - 1; l >= 1; --l) { win0[l] = win0[l - 1]; win1[l] = win1[l - 1]; } \
    win0[0] = raw0 * inv; win1[0] = raw1 * inv;                                \
    {                                                                          \
      float wm = fmaxf(raw0, raw1);                                            \
      wm = fmaxf(wm, __shfl_xor(wm, 1)); wm = fmaxf(wm, __shfl_xor(wm, 2));    \
      wm = fmaxf(wm, __shfl_xor(wm, 4)); wm = fmaxf(wm, __shfl_xor(wm, 8));    \
      if (lane == 0) cells[CW][w] = wm;                                        \
    }                                                                          \
    {                                                                          \
      float S0 = 0.f, S1 = 0.f;                                                \
      SDOT(hx0, win0, S0);                                                     \
      SDOT(hx1, win1, S1);                                                     \
      if ((rr) + 1 == xl) { cap0 = S0; cap1 = S1; capC = C; }                  \
      if (lane < 16) {                                                         \
        S_lds[WB][z0] = f_to_bf16u(S0); S_lds[WB][z1] = f_to_bf16u(S1);        \
      }                                                                        \
    }                                                                          \
    {                                                                          \
      const int np = ((rr) + 3 <= 511) ? (rr) + 3 : 511;                       \
      const uint2* p0 = (const uint2*)(hbase + ((size_t)np * ZB + z0) * 6);    \
      const uint2* p1 = (const uint2*)(hbase + ((size_t)np * ZB + z1) * 6);    \
      _Pragma("unroll")                                                        \
      for (int i = 0; i < 3; ++i) { hx0[i] = p0[i]; hx1[i] = p1[i]; }          \
    }                                                                          \
    BAR();                                                                     \
  } while (0)

#pragma unroll 1
  for (int r = 1; r <= 509; r += 2) {
    REGION(r, 1, 0, 0, 1, hE0, hE1);
    REGION(r + 1, 0, 1, 1, 0, hO0, hO1);
  }
#undef REGION
#undef SDOT

  // epilogue: out[b] = capC + log(sum_z cap_z); xl==0 -> 0
  {
    float v = cap0 + cap1;
    v += __shfl_xor(v, 1); v += __shfl_xor(v, 2);
    v += __shfl_xor(v, 4); v += __shfl_xor(v, 8);
    if (lane == 0) red4[w] = v;
  }
  __syncthreads();
  if (t == 0) {
    float tot = 0.f;
#pragma unroll
    for (int i = 0; i < 8; ++i) tot += red4[i];
    out[b] = (xl == 0) ? 0.f : (__logf(tot) + capC);
  }
}

extern "C" void kernel_launch(void* const* d_in, const int* in_sizes, int n_in,
                              void* d_out, int out_size, void* d_ws, size_t ws_size,
                              hipStream_t stream) {
  (void)in_sizes; (void)n_in; (void)out_size; (void)ws_size;
  const int* xlen = (const int*)d_in[1];
  const int* ng = (const int*)d_in[2];
  const float* emb = (const float*)d_in[3];
  const float* zpz = (const float*)d_in[4];
  const float* lpz = (const float*)d_in[5];
  float* out = (float*)d_out;

  char* ws = (char*)d_ws;
  unsigned int* H2 = (unsigned int*)ws;
  size_t off = (size_t)BB * TB * ZB * 6 * 4;  // 48 MiB
  float* part = (float*)(ws + off); off += (size_t)LB * NCHUNK * ZB * 4;
  unsigned short* Bimg = (unsigned short*)(ws + off); off += (size_t)16 * 8 * 64 * 8 * 2;
  float* Pexp = (float*)(ws + off); off += (size_t)ZB * ZB * 4;
  float* logZ = (float*)(ws + off); off += (size_t)LB * ZB * 4;
  float* lseZ = (float*)(ws + off); off += (size_t)ZB * 4;
  float* lt = (float*)(ws + off); off += (size_t)LB * ZB * 4;
  float* ltmz = (float*)(ws + off); off += (size_t)LB * ZB * 4;

  k1_sumexp<<<dim3(LB * NCHUNK), dim3(512), 0, stream>>>(emb, part);
  k2_combine<<<dim3(LB + 1 + ZB), dim3(ZB), 0, stream>>>(part, zpz, lpz, logZ, lseZ,
                                                         Pexp, Bimg);
  k3_tables<<<dim3(LB), dim3(ZB), 0, stream>>>(logZ, lseZ, lpz, lt, ltmz);
  k4_build<<<dim3(TB - 1, BB), dim3(ZB), 0, stream>>>(ng, emb, lt, ltmz, H2);
  k5_forward<<<dim3(BB), dim3(512), 0, stream>>>(Pexp, Bimg, H2, xlen, out);
}

// Round 10
// 582.859 us; speedup vs baseline: 1.2134x; 1.0279x over previous
//
#include <hip/hip_runtime.h>

// HSMM forward, scaled linear recurrence.
// R10: shorten the serial region chain of R9 (absmax 0): (1) bookkeeping +
// win-shift + partial SDOT (l>=1) hoisted BEFORE the MFMA result is consumed
// -- post-MFMA path is raw->win[0]->1 FMA->pack->write; (2) MFMA split into
// 4 independent 4-deep chains; (3) per-wave max via DPP (quad_perm/row_ror,
// VALU-only) instead of 4x ds_swizzle shfl that had to drain pre-barrier.
// Numerics identical to R9 up to FP summation order.
// ws: H2 u32[16][512][256][6] (48MiB); part f32[11][64][256]; Bimg bf16 128KB;
//     Pexp f32[256][256]; logZ[11][256]; lseZ[256]; lt[11][256]; ltmz[11][256].

#define VV 50000
#define ZB 256
#define LB 11
#define BB 16
#define TB 512
#define NCHUNK 64
#define CROWS 782  // ceil(VV/NCHUNK)

typedef float v4f __attribute__((ext_vector_type(4)));
typedef short bs8 __attribute__((ext_vector_type(8)));

static __device__ __forceinline__ float bf16u_to_f(unsigned short u) {
  return __uint_as_float(((unsigned int)u) << 16);
}
static __device__ __forceinline__ unsigned short f_to_bf16u(float f) {
  unsigned int b = __float_as_uint(f);
  b += 0x7FFFu + ((b >> 16) & 1u);
  return (unsigned short)(b >> 16);
}
static __device__ __forceinline__ void unp(unsigned int u, float& lo, float& hi) {
  lo = __uint_as_float(u << 16);
  hi = __uint_as_float(u & 0xFFFF0000u);
}
template <int CTRL>
static __device__ __forceinline__ float dppmax(float x) {
  const int y = __builtin_amdgcn_update_dpp(0, __float_as_int(x), CTRL, 0xF, 0xF, true);
  return fmaxf(x, __int_as_float(y));
}
// max over each 16-lane row (cols of one MFMA tile): xor1, xor2, ror4, ror8
static __device__ __forceinline__ float rowmax16(float x) {
  x = dppmax<0xB1>(x);   // quad_perm [1,0,3,2]
  x = dppmax<0x4E>(x);   // quad_perm [2,3,0,1]
  x = dppmax<0x124>(x);  // row_ror:4
  x = dppmax<0x128>(x);  // row_ror:8
  return x;
}

#define BAR() do { asm volatile("s_waitcnt lgkmcnt(0)" ::: "memory"); \
                   __builtin_amdgcn_s_barrier();                      \
                   asm volatile("" ::: "memory"); } while (0)

// ---- K1: per-chunk sum of exp(emb) over v (no-max: emb ~ N(0,1), safe in f32)
__global__ void k1_sumexp(const float* __restrict__ emb, float* __restrict__ part) {
  const int l = blockIdx.x / NCHUNK;
  const int c = blockIdx.x % NCHUNK;
  const int t = threadIdx.x;           // 512 threads
  const int zi = (t & 63) * 4;
  const int ro = t >> 6;               // 0..7
  const int v0 = c * CROWS;
  const int v1 = (v0 + CROWS < VV) ? (v0 + CROWS) : VV;
  const float* base = emb + (size_t)l * VV * ZB;
  float a0 = 0.f, a1 = 0.f, a2 = 0.f, a3 = 0.f;
  int v = v0 + ro;
  for (; v + 24 < v1; v += 32) {
    float4 x0 = *(const float4*)(base + (size_t)(v)*ZB + zi);
    float4 x1 = *(const float4*)(base + (size_t)(v + 8) * ZB + zi);
    float4 x2 = *(const float4*)(base + (size_t)(v + 16) * ZB + zi);
    float4 x3 = *(const float4*)(base + (size_t)(v + 24) * ZB + zi);
    a0 += __expf(x0.x) + __expf(x1.x) + __expf(x2.x) + __expf(x3.x);
    a1 += __expf(x0.y) + __expf(x1.y) + __expf(x2.y) + __expf(x3.y);
    a2 += __expf(x0.z) + __expf(x1.z) + __expf(x2.z) + __expf(x3.z);
    a3 += __expf(x0.w) + __expf(x1.w) + __expf(x2.w) + __expf(x3.w);
  }
  for (; v < v1; v += 8) {
    float4 x0 = *(const float4*)(base + (size_t)v * ZB + zi);
    a0 += __expf(x0.x); a1 += __expf(x0.y); a2 += __expf(x0.z); a3 += __expf(x0.w);
  }
  __shared__ float red[8][ZB];
  red[ro][zi] = a0; red[ro][zi + 1] = a1; red[ro][zi + 2] = a2; red[ro][zi + 3] = a3;
  __syncthreads();
  if (t < ZB) {
    float s = 0.f;
#pragma unroll
    for (int r = 0; r < 8; ++r) s += red[r][t];
    part[((size_t)l * NCHUNK + c) * ZB + t] = s;
  }
}

// ---- K2: combine partials -> logZ; lse over l of l_per_z; Pexp rows + Bimg
__global__ void k2_combine(const float* __restrict__ part, const float* __restrict__ zpz,
                           const float* __restrict__ lpz, float* __restrict__ logZ,
                           float* __restrict__ lseZ, float* __restrict__ Pexp,
                           unsigned short* __restrict__ Bimg) {
  const int bid = blockIdx.x;
  const int t = threadIdx.x;  // 256
  if (bid < LB) {
    float s = 0.f;
    for (int c = 0; c < NCHUNK; ++c) s += part[((size_t)bid * NCHUNK + c) * ZB + t];
    logZ[bid * ZB + t] = __logf(s);
  } else if (bid == LB) {
    float lv[LB]; float m = -1e30f;
#pragma unroll
    for (int l = 0; l < LB; ++l) { lv[l] = lpz[t * LB + l]; m = fmaxf(m, lv[l]); }
    float s = 0.f;
#pragma unroll
    for (int l = 0; l < LB; ++l) s += __expf(lv[l] - m);
    lseZ[t] = m + __logf(s);
  } else {
    const int r = bid - (LB + 1);  // z (row of P)
    const float x = zpz[r * ZB + t];
    __shared__ float sA[4], sB[4];
    float m = x;
#pragma unroll
    for (int off = 32; off >= 1; off >>= 1) m = fmaxf(m, __shfl_xor(m, off, 64));
    if ((t & 63) == 0) sA[t >> 6] = m;
    __syncthreads();
    m = fmaxf(fmaxf(sA[0], sA[1]), fmaxf(sA[2], sA[3]));
    const float e = __expf(x - m);
    float s = e;
#pragma unroll
    for (int off = 32; off >= 1; off >>= 1) s += __shfl_xor(s, off, 64);
    if ((t & 63) == 0) sB[t >> 6] = s;
    __syncthreads();
    const float tot = sB[0] + sB[1] + sB[2] + sB[3];
    const float P = e / tot;
    Pexp[r * ZB + t] = P;
    // B-fragment image for k5: frag(tile, slice), lane = g*16 + col, elem = ii
    // holds B[k = slice*32 + g*8 + ii][col] = P[r][t].
    const int tile = t >> 4, cl = t & 15;
    const int slice = r >> 5, g = (r >> 3) & 3, ii = r & 7;
    Bimg[((size_t)(tile * 8 + slice) * 64 + (g * 16 + cl)) * 8 + ii] = f_to_bf16u(P);
  }
}

// ---- K3: small tables lt = exp(l_term), ltmz = l_term - logZ
__global__ void k3_tables(const float* __restrict__ logZ, const float* __restrict__ lseZ,
                          const float* __restrict__ lpz, float* __restrict__ lt,
                          float* __restrict__ ltmz) {
  const int l = blockIdx.x; const int z = threadIdx.x;
  const float ll = lpz[z * LB + l] - lseZ[z];
  lt[l * ZB + z] = __expf(ll);
  ltmz[l * ZB + z] = ll - logZ[l * ZB + z];
}

// ---- K4: build shift-aligned emissions, PAIR-PACKED: H2[b][n][z][6] (u32)
__global__ void k4_build(const int* __restrict__ ng, const float* __restrict__ emb,
                         const float* __restrict__ lt, const float* __restrict__ ltmz,
                         unsigned int* __restrict__ H2) {
  const int n = blockIdx.x + 1;
  const int b = blockIdx.y;
  const int z = threadIdx.x;  // 256
  float h[12];
#pragma unroll
  for (int l = 0; l < LB; ++l) {
    const int s = n - 1 - l;
    float hv = 0.f;
    if (s >= 0) {
      const int id = ng[((size_t)l * BB + b) * TB + s];
      if (id == 0) hv = lt[l * ZB + z];
      else if (id != 1) hv = __expf(emb[((size_t)l * VV + id) * ZB + z] + ltmz[l * ZB + z]);
    }
    h[l] = hv;
  }
  h[11] = 0.f;
  unsigned int* dst = H2 + ((size_t)(b * TB + n) * ZB + z) * 6;
#pragma unroll
  for (int i = 0; i < 6; ++i)
    dst[i] = (unsigned int)f_to_bf16u(h[2 * i]) |
             ((unsigned int)f_to_bf16u(h[2 * i + 1]) << 16);
}

// ---- K5: merged single-barrier scan. 512 thr/block, one block per batch b.
// wave w owns tiles {w, w+8}; lane owns z0 = w*16+(lane&15), z1 = z0+128.
__global__ __launch_bounds__(512, 1)
void k5_forward(const float* __restrict__ Pexp, const unsigned short* __restrict__ Bimg,
                const unsigned int* __restrict__ H2,
                const int* __restrict__ xlen, float* __restrict__ out) {
  const int b = blockIdx.x;
  const int t = threadIdx.x;
  const int w = t >> 6;
  const int lane = t & 63;
  const int col = lane & 15;
  const int g4 = (lane >> 4) << 4;          // g*16 bytes for A-read
  const int z0 = w * 16 + col;              // tile w
  const int z1 = (w + 8) * 16 + col;        // tile w+8

  __shared__ __align__(16) unsigned short S_lds[2][ZB];  // S as bf16, dbuf
  __shared__ __align__(16) float cells[2][8];            // per-wave stale max
  __shared__ float red4[8];

  // resident B = P fragments pinned to AGPRs (2 tiles x 8 slices).
  bs8 frag0[8], frag1[8];
#pragma unroll
  for (int s = 0; s < 8; ++s) {
    frag0[s] = *((const bs8*)Bimg + (size_t)(w * 8 + s) * 64 + lane);
    frag1[s] = *((const bs8*)Bimg + (size_t)((w + 8) * 8 + s) * 64 + lane);
    asm volatile("" : "+a"(frag0[s]));
    asm volatile("" : "+a"(frag1[s]));
  }

  const int xl = xlen[b];

  // m0 = max_z P[0][z]
  const float p00 = Pexp[z0], p01 = Pexp[z1];
  {
    float pm = fmaxf(p00, p01);
    pm = fmaxf(pm, __shfl_xor(pm, 1)); pm = fmaxf(pm, __shfl_xor(pm, 2));
    pm = fmaxf(pm, __shfl_xor(pm, 4)); pm = fmaxf(pm, __shfl_xor(pm, 8));
    if (lane == 0) cells[0][w] = pm;
  }
  __syncthreads();
  float m0;
  {
    const float4 cA = *(const float4*)&cells[0][0];
    const float4 cB = *(const float4*)&cells[0][4];
    m0 = fmaxf(fmaxf(fmaxf(cA.x, cA.y), fmaxf(cA.z, cA.w)),
               fmaxf(fmaxf(cB.x, cB.y), fmaxf(cB.z, cB.w)));
  }
  __syncthreads();
  if (lane == 0) { cells[0][w] = 1.f; cells[1][w] = 1.f; }

  // state init
  float win0[LB], win1[LB], wl[LB];
  float C = __logf(m0), cap0 = 0.f, cap1 = 0.f, capC = 0.f;
  win0[0] = p00 / m0; win1[0] = p01 / m0;
  wl[0] = 1.f;
#pragma unroll
  for (int l = 1; l < LB; ++l) { win0[l] = 0.f; win1[l] = 0.f; wl[l] = 0.f; }

  const unsigned int* hbase = H2 + (size_t)b * TB * ZB * 6;

  // S(1) = H(1)[l=0]*win[0]
  {
    const float S0 = bf16u_to_f((unsigned short)hbase[((size_t)1 * ZB + z0) * 6]) * win0[0];
    const float S1 = bf16u_to_f((unsigned short)hbase[((size_t)1 * ZB + z1) * 6]) * win1[0];
    if (xl == 1) { cap0 = S0; cap1 = S1; capC = C; }
    if (lane < 16) { S_lds[1][z0] = f_to_bf16u(S0); S_lds[1][z1] = f_to_bf16u(S1); }
  }

  // H prefetch buffers (uint2 x3 each): hE = H(2) (odd regions), hO = H(3)
  uint2 hE0[3], hE1[3], hO0[3], hO1[3];
#pragma unroll
  for (int i = 0; i < 3; ++i) {
    hE0[i] = ((const uint2*)(hbase + ((size_t)2 * ZB + z0) * 6))[i];
    hE1[i] = ((const uint2*)(hbase + ((size_t)2 * ZB + z1) * 6))[i];
    hO0[i] = ((const uint2*)(hbase + ((size_t)3 * ZB + z0) * 6))[i];
    hO1[i] = ((const uint2*)(hbase + ((size_t)3 * ZB + z1) * 6))[i];
  }
  BAR();  // S(1), cells init visible

#define UNP12(hx, h)                                                           \
  { unp(hx[0].x, h[0], h[1]); unp(hx[0].y, h[2], h[3]);                        \
    unp(hx[1].x, h[4], h[5]); unp(hx[1].y, h[6], h[7]);                        \
    unp(hx[2].x, h[8], h[9]); unp(hx[2].y, h[10], h[11]); }

// Region rr: MFMA of S(rr) -> raw(rr); state update; S(rr+1) compute+publish.
#define REGION(rr, RB, WB, CR, CW, hx0, hx1)                                   \
  do {                                                                         \
    /* cells read first, then A-reads (in-order lgkm returns) */               \
    const float4 cA = *(const float4*)&cells[CR][0];                           \
    const float4 cB = *(const float4*)&cells[CR][4];                           \
    const bs8* ap = (const bs8*)((const char*)&S_lds[RB][0] + g4);             \
    bs8 ar[8];                                                                 \
    _Pragma("unroll")                                                          \
    for (int s = 0; s < 8; ++s) ar[s] = ap[s * 4];                             \
    /* MFMA: 4 independent 4-deep chains */                                    \
    v4f aA0 = {0.f,0.f,0.f,0.f}, aB0 = {0.f,0.f,0.f,0.f};                      \
    v4f aA1 = {0.f,0.f,0.f,0.f}, aB1 = {0.f,0.f,0.f,0.f};                      \
    _Pragma("unroll")                                                          \
    for (int s = 0; s < 4; ++s) {                                              \
      aA0 = __builtin_amdgcn_mfma_f32_16x16x32_bf16(ar[s], frag0[s], aA0, 0, 0, 0);     \
      aA1 = __builtin_amdgcn_mfma_f32_16x16x32_bf16(ar[s], frag1[s], aA1, 0, 0, 0);     \
      aB0 = __builtin_amdgcn_mfma_f32_16x16x32_bf16(ar[s + 4], frag0[s + 4], aB0, 0, 0, 0); \
      aB1 = __builtin_amdgcn_mfma_f32_16x16x32_bf16(ar[s + 4], frag1[s + 4], aB1, 0, 0, 0); \
    }                                                                          \
    /* ---- pre-raw work (independent of MFMA result) ---- */                  \
    float mx = fmaxf(fmaxf(fmaxf(cA.x, cA.y), fmaxf(cA.z, cA.w)),              \
                     fmaxf(fmaxf(cB.x, cB.y), fmaxf(cB.z, cB.w)));             \
    mx = fmaxf(mx, 1e-35f);                                                    \
    const float inv = 1.0f / mx;                                               \
    const float delta = __logf(mx);                                            \
    float mw = wl[0];                                                          \
    _Pragma("unroll")                                                          \
    for (int l = 1; l < LB - 1; ++l) mw = fmaxf(mw, wl[l]);                    \
    const float a = fmaxf(delta, __logf(fmaxf(mw, 1e-37f)));                   \
    const float es = __expf(-a);                                               \
    _Pragma("unroll")                                                          \
    for (int l = LB - 1; l >= 1; --l) wl[l] = wl[l - 1] * es;                  \
    wl[0] = __expf(delta - a);                                                 \
    C += a;                                                                    \
    _Pragma("unroll")                                                          \
    for (int l = LB - 1; l >= 1; --l) { win0[l] = win0[l - 1]; win1[l] = win1[l - 1]; } \
    float h0[12], h1[12];                                                      \
    UNP12(hx0, h0); UNP12(hx1, h1);                                            \
    float c00 = 0.f, c01 = 0.f, c10 = 0.f, c11 = 0.f;                          \
    _Pragma("unroll")                                                          \
    for (int l = 1; l < LB; l += 2) {                                          \
      c00 = fmaf(wl[l] * h0[l], win0[l], c00);                                 \
      c10 = fmaf(wl[l] * h1[l], win1[l], c10);                                 \
    }                                                                          \
    _Pragma("unroll")                                                          \
    for (int l = 2; l < LB; l += 2) {                                          \
      c01 = fmaf(wl[l] * h0[l], win0[l], c01);                                 \
      c11 = fmaf(wl[l] * h1[l], win1[l], c11);                                 \
    }                                                                          \
    const float S0p = c00 + c01, S1p = c10 + c11;                              \
    const float h00w = h0[0] * wl[0], h10w = h1[0] * wl[0];                    \
    /* prefetch H for region rr+2 */                                           \
    {                                                                          \
      const int np = ((rr) + 3 <= 511) ? (rr) + 3 : 511;                       \
      const uint2* p0 = (const uint2*)(hbase + ((size_t)np * ZB + z0) * 6);    \
      const uint2* p1 = (const uint2*)(hbase + ((size_t)np * ZB + z1) * 6);    \
      _Pragma("unroll")                                                        \
      for (int i = 0; i < 3; ++i) { hx0[i] = p0[i]; hx1[i] = p1[i]; }          \
    }                                                                          \
    /* ---- post-raw (short path) ---- */                                      \
    const float raw0 = aA0[0] + aB0[0];                                        \
    const float raw1 = aA1[0] + aB1[0];                                        \
    win0[0] = raw0 * inv; win1[0] = raw1 * inv;                                \
    const float S0 = fmaf(h00w, win0[0], S0p);                                 \
    const float S1 = fmaf(h10w, win1[0], S1p);                                 \
    if ((rr) + 1 == xl) { cap0 = S0; cap1 = S1; capC = C; }                    \
    if (lane < 16) {                                                           \
      S_lds[WB][z0] = f_to_bf16u(S0); S_lds[WB][z1] = f_to_bf16u(S1);          \
    }                                                                          \
    /* wm via DPP row-max (VALU only, no lgkm drain) */                        \
    {                                                                          \
      const float wm = rowmax16(fmaxf(raw0, raw1));                            \
      if (lane == 0) cells[CW][w] = wm;                                        \
    }                                                                          \
    BAR();                                                                     \
  } while (0)

#pragma unroll 1
  for (int r = 1; r <= 509; r += 2) {
    REGION(r, 1, 0, 0, 1, hE0, hE1);
    REGION(r + 1, 0, 1, 1, 0, hO0, hO1);
  }
#undef REGION
#undef UNP12

  // epilogue: out[b] = capC + log(sum_z cap_z); xl==0 -> 0
  {
    float v = cap0 + cap1;
    v += __shfl_xor(v, 1); v += __shfl_xor(v, 2);
    v += __shfl_xor(v, 4); v += __shfl_xor(v, 8);
    if (lane == 0) red4[w] = v;
  }
  __syncthreads();
  if (t == 0) {
    float tot = 0.f;
#pragma unroll
    for (int i = 0; i < 8; ++i) tot += red4[i];
    out[b] = (xl == 0) ? 0.f : (__logf(tot) + capC);
  }
}

extern "C" void kernel_launch(void* const* d_in, const int* in_sizes, int n_in,
                              void* d_out, int out_size, void* d_ws, size_t ws_size,
                              hipStream_t stream) {
  (void)in_sizes; (void)n_in; (void)out_size; (void)ws_size;
  const int* xlen = (const int*)d_in[1];
  const int* ng = (const int*)d_in[2];
  const float* emb = (const float*)d_in[3];
  const float* zpz = (const float*)d_in[4];
  const float* lpz = (const float*)d_in[5];
  float* out = (float*)d_out;

  char* ws = (char*)d_ws;
  unsigned int* H2 = (unsigned int*)ws;
  size_t off = (size_t)BB * TB * ZB * 6 * 4;  // 48 MiB
  float* part = (float*)(ws + off); off += (size_t)LB * NCHUNK * ZB * 4;
  unsigned short* Bimg = (unsigned short*)(ws + off); off += (size_t)16 * 8 * 64 * 8 * 2;
  float* Pexp = (float*)(ws + off); off += (size_t)ZB * ZB * 4;
  float* logZ = (float*)(ws + off); off += (size_t)LB * ZB * 4;
  float* lseZ = (float*)(ws + off); off += (size_t)ZB * 4;
  float* lt = (float*)(ws + off); off += (size_t)LB * ZB * 4;
  float* ltmz = (float*)(ws + off); off += (size_t)LB * ZB * 4;

  k1_sumexp<<<dim3(LB * NCHUNK), dim3(512), 0, stream>>>(emb, part);
  k2_combine<<<dim3(LB + 1 + ZB), dim3(ZB), 0, stream>>>(part, zpz, lpz, logZ, lseZ,
                                                         Pexp, Bimg);
  k3_tables<<<dim3(LB), dim3(ZB), 0, stream>>>(logZ, lseZ, lpz, lt, ltmz);
  k4_build<<<dim3(TB - 1, BB), dim3(ZB), 0, stream>>>(ng, emb, lt, ltmz, H2);
  k5_forward<<<dim3(BB), dim3(512), 0, stream>>>(Pexp, Bimg, H2, xlen, out);
}